// Round 8
// baseline (2260.150 us; speedup 1.0000x reference)
//
#include <hip/hip_runtime.h>
#include <hip/hip_cooperative_groups.h>

typedef unsigned int uint;
typedef unsigned short ushort;

#define NLAT 361
#define NLON 720
#define NNZT 65536
#define CIN 64
#define COUT 64
#define NK 9
#define PADL 784     // 720 + 64 wrap pad
#define ROWCAP 384   // max row population ~230 (15 sigma margin)
#define CKTOT 576    // CIN*NK
#define YPS 168      // Yp row stride in ushorts (336B)
#define WTS 640      // Wt row stride in ushorts (4 chunks x 160)
#define XROWB (16*PADL*8)   // 100352 bytes per (b,lat) row of xb
#define GRIDC 722    // blocks = (lo, b); 3 pq-items each
#define OCAP 128     // per-wave owned-list capacity (mean ~60, 7 sigma margin)

typedef __attribute__((ext_vector_type(8))) short short8v;   // 8 bf16
typedef __attribute__((ext_vector_type(4))) float f32x4;     // MFMA C/D

__device__ __forceinline__ float bfu(uint u){ return __uint_as_float(u<<16); }
__device__ __forceinline__ float bfh(uint u){ return __uint_as_float(u & 0xffff0000u); }
__device__ __forceinline__ ushort f2bf(float f){
  uint b = __float_as_uint(f);
  return (ushort)((b + 0x7fffu + ((b>>16)&1u)) >> 16);
}
__device__ __forceinline__ uint packbf2(float f0, float f1){
  uint b0 = __float_as_uint(f0), b1 = __float_as_uint(f1);
  uint r0 = (b0 + 0x7fffu + ((b0>>16)&1u)) >> 16;
  uint r1 = ((b1 + 0x7fffu + ((b1>>16)&1u)) >> 16) << 16;
  return r0 | r1;
}

// ---- CSR build: per-row list, LAT-SORTED (whole row), k packed in meta.y ----
// meta.x = lat*XROWB + lon*8 (monotone in (lat,lon))
// meta.y = (val & 0xffffc000) | (k<<10) | lon   (val keeps 9 mantissa bits)
// kptr_g[lo*10 + k] = count of k in row; [9] = n
__global__ __launch_bounds__(256) void k_csr(const int* __restrict__ ker, const int* __restrict__ row,
                                             const int* __restrict__ col, const float* __restrict__ vals,
                                             int2* __restrict__ meta_g, int* __restrict__ kptr_g){
  const int lo = blockIdx.x, tid = threadIdx.x;
  __shared__ int cnt[256];
  __shared__ int2 list[ROWCAP];
  __shared__ int kc[NK];
  __shared__ int ntot;
  int c=0;
  for (int i=tid;i<NNZT;i+=256) if (row[i]==lo) c++;
  cnt[tid]=c;
  if (tid<NK) kc[tid]=0;
  __syncthreads();
  if (tid==0){ int run=0; for (int t=0;t<256;t++){ int tmp=cnt[t]; cnt[t]=run; run+=tmp; } ntot=run; }
  __syncthreads();
  int off=cnt[tid];
  for (int i=tid;i<NNZT;i+=256) if (row[i]==lo){
    if (off<ROWCAP){
      int cc=col[i]; int lat=cc/NLON, lon=cc-lat*NLON;
      int kk=ker[i];
      uint vb=__float_as_uint(vals[i])&0xffffc000u;
      list[off]=make_int2(lat*XROWB+lon*8, (int)(vb|((uint)kk<<10)|(uint)lon));
      atomicAdd(&kc[kk],1);
    }
    off++;
  }
  __syncthreads();
  int n = ntot; if (n>ROWCAP) n=ROWCAP;
  // deterministic rank sort by (x, insertion idx)
  for (int i=tid;i<n;i+=256){
    uint xi=(uint)list[i].x; int r=0;
    for (int j=0;j<n;j++){
      uint xj=(uint)list[j].x;
      r += (xj<xi) || (xj==xi && j<i);
    }
    meta_g[lo*ROWCAP+r]=list[i];
  }
  if (tid<NK) kptr_g[lo*10+tid]=kc[tid];
  if (tid==NK) kptr_g[lo*10+9]=n;
}

// -- x -> bf16, layout [b][lat][cquad(16)][784 pos][4 ch], wrap-padded --------
__global__ __launch_bounds__(256) void k_xb(const float* __restrict__ x, ushort* __restrict__ xb){
  const int bid=blockIdx.x, tid=threadIdx.x;
  const int b=bid/NLAT, lat=bid-b*NLAT;
  const float* xs = x + (size_t)b*CIN*NLAT*NLON + (size_t)lat*NLON;
  ushort* xd = xb + (size_t)(b*NLAT+lat)*16*PADL*4;
  const size_t S=(size_t)NLAT*NLON;
  for (int idx=tid; idx<16*PADL; idx+=256){
    int cq=idx/PADL, j=idx-cq*PADL;
    int jj = (j<NLON)? j : j-NLON;
    const float* xc = xs + (size_t)(cq*4)*S + jj;
    uint lo32 = packbf2(xc[0], xc[S]);
    uint hi32 = packbf2(xc[2*S], xc[3*S]);
    *(uint2*)(xd + (size_t)(cq*PADL + j)*4) = make_uint2(lo32, hi32);
  }
}

// -- W -> bf16, kk-major ck order: wt[oc][chunk*160 + q*36 + kk*4 + j] --------
// source: w[oc][(chunk*16 + q*4 + j)*9 + kk]; slots 144..159 zero
__global__ __launch_bounds__(256) void k_wt(const float* __restrict__ w, ushort* __restrict__ wt){
  int idx = blockIdx.x*256 + threadIdx.x;
  if (idx >= COUT*WTS) return;
  int oc = idx/WTS, ckl = idx-oc*WTS;
  int chunk = ckl/160, q = ckl-chunk*160;
  ushort v = 0;
  if (q < 144){
    int wvq=q/36, r=q-wvq*36;
    int kk=r>>2, j=r&3;
    v = f2bf(w[oc*CKTOT + (chunk*16 + wvq*4 + j)*NK + kk]);
  }
  wt[oc*WTS + ckl] = v;
}

// ------------- phase-aligned gather + MFMA main kernel -----------------------
// block = (lo, b); items = 3 pq's. SYNC=1: cooperative grid.sync per cell.
template<int USE_XB, int SYNC>
__global__ __launch_bounds__(256,3) void k_coop(const float* __restrict__ x, const ushort* __restrict__ xb,
    const int2* __restrict__ meta_g, const int* __restrict__ kptr_g,
    const ushort* __restrict__ wt, const float* __restrict__ bias, float* __restrict__ out){
  const int wid=blockIdx.x, tid=threadIdx.x;
  const int lane=tid&63, wv=tid>>6, l15=lane&15, kg=lane>>4;
  const int lo=wid>>1, b=wid&1;

  __shared__ int2 meta[ROWCAP];                    // 3072 B
  __shared__ __align__(16) ushort Yp[64*YPS];      // 21504 B
  __shared__ ushort olist[4*OCAP];                 // 1024 B
                                                   // total 25600 B -> 6 blocks by LDS

  int n = kptr_g[lo*10+9]; if (n>ROWCAP) n=ROWCAP;
  for (int i=tid;i<n;i+=256) meta[i]=meta_g[lo*ROWCAP+i];
  // balanced contiguous partition of k=0..8 into 4 waves (sizes 3,2,2,2 rotated)
  int kbase, klen;
  {
    int P[10]; P[0]=0;
    #pragma unroll
    for (int k=0;k<9;k++) P[k+1]=P[k]+kptr_g[lo*10+k];
    const int Bn[4][5]={{0,3,5,7,9},{0,2,5,7,9},{0,2,4,7,9},{0,2,4,6,9}};
    int best=1<<30, br=0;
    #pragma unroll
    for (int r=0;r<4;r++){
      int m0=P[Bn[r][1]]-P[0], m1=P[Bn[r][2]]-P[Bn[r][1]];
      int m2=P[Bn[r][3]]-P[Bn[r][2]], m3=P[9]-P[Bn[r][3]];
      int mx=max(max(m0,m1),max(m2,m3));
      if (mx<best){best=mx;br=r;}
    }
    kbase=Bn[br][wv]; klen=Bn[br][wv+1]-Bn[br][wv];
  }
  // zero Yp pad rows ck 144..159 (never rewritten)
  for (int idx=tid; idx<64*8; idx+=256){
    int p=idx>>3, j=idx&7;
    *(uint*)((char*)Yp + p*(YPS*2) + 288 + j*4)=0;
  }
  __syncthreads();
  // per-wave owned index list (lat-sorted subset with k in [kbase, kbase+klen))
  int ocount=0;
  for (int i=0;i<n;i++){
    int k=(int)(((uint)meta[i].y>>10)&15u);
    if ((unsigned)(k-kbase)<(unsigned)klen && ocount<OCAP){
      if (lane==0) olist[wv*OCAP+ocount]=(ushort)i;
      ocount++;
    }
  }
  __syncthreads();

  const char* xb8 = (const char*)xb + (size_t)b*NLAT*(size_t)XROWB;
  const char* wtb = (const char*)wt + ((wv*16+l15)*WTS + kg*8)*2;
  const char* ypb = (const char*)Yp + l15*(YPS*2) + kg*16;
  char* ydst = (char*)Yp + lane*(YPS*2);
  const ushort* ol = &olist[wv*OCAP];
  const int SS = NLAT*NLON;

#define C16(S) { \
  acc[0][0][S]+=v*bfu(u0.x); acc[0][1][S]+=v*bfh(u0.x); acc[0][2][S]+=v*bfu(u0.y); acc[0][3][S]+=v*bfh(u0.y); \
  acc[1][0][S]+=v*bfu(u1.x); acc[1][1][S]+=v*bfh(u1.x); acc[1][2][S]+=v*bfu(u1.y); acc[1][3][S]+=v*bfh(u1.y); \
  acc[2][0][S]+=v*bfu(u2.x); acc[2][1][S]+=v*bfh(u2.x); acc[2][2][S]+=v*bfu(u2.y); acc[2][3][S]+=v*bfh(u2.y); \
  acc[3][0][S]+=v*bfu(u3.x); acc[3][1][S]+=v*bfh(u3.x); acc[3][2][S]+=v*bfu(u3.y); acc[3][3][S]+=v*bfh(u3.y); }
#define C16F(S) { \
  acc[0][0][S]+=v*x[fb]; acc[0][1][S]+=v*x[fb+SS]; acc[0][2][S]+=v*x[fb+2*SS]; acc[0][3][S]+=v*x[fb+3*SS]; \
  acc[1][0][S]+=v*x[fb+4*SS]; acc[1][1][S]+=v*x[fb+5*SS]; acc[1][2][S]+=v*x[fb+6*SS]; acc[1][3][S]+=v*x[fb+7*SS]; \
  acc[2][0][S]+=v*x[fb+8*SS]; acc[2][1][S]+=v*x[fb+9*SS]; acc[2][2][S]+=v*x[fb+10*SS]; acc[2][3][S]+=v*x[fb+11*SS]; \
  acc[3][0][S]+=v*x[fb+12*SS]; acc[3][1][S]+=v*x[fb+13*SS]; acc[3][2][S]+=v*x[fb+14*SS]; acc[3][3][S]+=v*x[fb+15*SS]; }

  f32x4 outacc[3][4];
  #pragma unroll
  for (int a=0;a<3;a++)
    #pragma unroll
    for (int c2=0;c2<4;c2++) outacc[a][c2]=(f32x4)0.f;

  for (int pt=0;pt<4;pt++){
    for (int chunk=0;chunk<4;chunk++){
      if constexpr (SYNC) cooperative_groups::this_grid().sync();  // phase alignment
      const char* xq0 = xb8 + (size_t)(chunk*4+0)*(PADL*8);
      const char* xq1 = xb8 + (size_t)(chunk*4+1)*(PADL*8);
      const char* xq2 = xb8 + (size_t)(chunk*4+2)*(PADL*8);
      const char* xq3 = xb8 + (size_t)(chunk*4+3)*(PADL*8);
      for (int it=0;it<3;it++){
        const int p0 = it*240 + pt*64;
        const uint thr = (uint)(NLON-p0);
        const uint lanep8 = (uint)(lane+p0)*8u;
        const bool act = (pt<3) || (lane<48);   // pt=3: lanes>=48 feed only discarded ptile3
        const int jmax = act ? ocount : 0;
        float acc[4][4][3];
        #pragma unroll
        for (int q=0;q<4;q++)
          #pragma unroll
          for (int j=0;j<4;j++)
            #pragma unroll
            for (int s=0;s<3;s++) acc[q][j][s]=0.f;

        for (int j2=0;j2<jmax;j2++){
          int i = ol[j2];
          int2 m = meta[i];
          uint ky = (uint)m.y;
          int slot = (int)((ky>>10)&15u) - kbase;
          float v = __uint_as_float(ky & 0xffffc000u);
          if (USE_XB){
            uint common = (uint)m.x + lanep8 + (((ky&0x3ffu) >= thr) ? (uint)-5760 : 0u);
            uint2 u0=*(const uint2*)(xq0+common);
            uint2 u1=*(const uint2*)(xq1+common);
            uint2 u2=*(const uint2*)(xq2+common);
            uint2 u3=*(const uint2*)(xq3+common);
            if (slot==0){ C16(0) } else if (slot==1){ C16(1) } else { C16(2) }
          } else {
            int lat=(int)(((uint)m.x)/(uint)XROWB);
            int s=(int)(ky&0x3ffu)+p0; s=(s>=NLON)?s-NLON:s;
            int widx=s+lane; widx=(widx>=NLON)?widx-NLON:widx;
            int fb=((b*CIN + chunk*16)*NLAT + lat)*NLON + widx;
            if (slot==0){ C16F(0) } else if (slot==1){ C16F(1) } else { C16F(2) }
          }
        }
        __syncthreads();   // previous item's MFMA done reading Yp
        if (act){
          #pragma unroll
          for (int s=0;s<3;s++){
            if (s<klen){
              int kk=kbase+s;
              #pragma unroll
              for (int q=0;q<4;q++){
                uint lo32=packbf2(acc[q][0][s],acc[q][1][s]);
                uint hi32=packbf2(acc[q][2][s],acc[q][3][s]);
                *(uint2*)(ydst + (q*36+kk*4)*2)=make_uint2(lo32,hi32);
              }
            }
          }
        }
        __syncthreads();   // Yp complete
        #pragma unroll
        for (int ptile=0;ptile<4;ptile++){
          #pragma unroll
          for (int ks=0;ks<5;ks++){
            short8v bf = *(const short8v*)(ypb + ptile*(16*YPS*2) + ks*64);
            short8v afk = *(const short8v*)(wtb + (chunk*160 + ks*32)*2);
            outacc[it][ptile]=__builtin_amdgcn_mfma_f32_16x16x32_bf16(afk,bf,outacc[it][ptile],0,0,0);
          }
        }
      }
    }
    // epilogue for this pt; D: col=l15 (p), row=kg*4+r (oc)
    #pragma unroll
    for (int it=0;it<3;it++){
      #pragma unroll
      for (int ptile=0;ptile<4;ptile++){
        const int pidx = pt*64 + ptile*16;
        if (pidx < 240){
          #pragma unroll
          for (int r=0;r<4;r++){
            int oc = wv*16 + kg*4 + r;
            out[((size_t)(b*COUT+oc)*NLAT + lo)*NLON + it*240 + pidx + l15]
              = outacc[it][ptile][r] + bias[oc];
          }
        }
        outacc[it][ptile]=(f32x4)0.f;
      }
    }
  }
#undef C16
#undef C16F
}

extern "C" void kernel_launch(void* const* d_in, const int* in_sizes, int n_in,
                              void* d_out, int out_size, void* d_ws, size_t ws_size,
                              hipStream_t stream){
  const float* x   =(const float*)d_in[0];
  const float* vals=(const float*)d_in[1];
  const float* w   =(const float*)d_in[2];
  const float* bias=(const float*)d_in[3];
  const int* ker=(const int*)d_in[4];
  const int* row=(const int*)d_in[5];
  const int* col=(const int*)d_in[6];
  float* outp=(float*)d_out;

  const size_t META_B=(size_t)NLAT*ROWCAP*sizeof(int2);
  const size_t KPTR_B=((size_t)NLAT*10*sizeof(int)+15)&~(size_t)15;
  const size_t WT_B=((size_t)COUT*WTS*sizeof(ushort)+15)&~(size_t)15;
  const size_t XB_B=(size_t)2*NLAT*16*PADL*4*sizeof(ushort);
  int2* meta_g=(int2*)d_ws;
  int*  kptr_g=(int*)((char*)d_ws+META_B);
  ushort* wt=(ushort*)((char*)d_ws+META_B+KPTR_B);
  ushort* xb=(ushort*)((char*)d_ws+META_B+KPTR_B+WT_B);
  const bool use_xb = ws_size >= META_B+KPTR_B+WT_B+XB_B;

  k_csr<<<dim3(NLAT), dim3(256), 0, stream>>>(ker,row,col,vals,meta_g,kptr_g);
  k_wt <<<dim3((COUT*WTS+255)/256), dim3(256), 0, stream>>>(w, wt);
  if (use_xb)
    k_xb<<<dim3(2*NLAT), dim3(256), 0, stream>>>(x, xb);

  // host-side capability + co-residency checks (capture-safe pure queries)
  int dev=0; (void)hipGetDevice(&dev);
  int coopAttr=0; (void)hipDeviceGetAttribute(&coopAttr, hipDeviceAttributeCooperativeLaunch, dev);
  int ncu=0; (void)hipDeviceGetAttribute(&ncu, hipDeviceAttributeMultiprocessorCount, dev);

  typedef void (*KFn)(const float*, const ushort*, const int2*, const int*,
                      const ushort*, const float*, float*);
  KFn fsync = use_xb ? (KFn)&k_coop<1,1> : (KFn)&k_coop<0,1>;
  int nb=0;
  (void)hipOccupancyMaxActiveBlocksPerMultiprocessor(&nb, fsync, 256, 0);

  bool coop = (coopAttr!=0) && ((long)nb*(long)ncu >= (long)GRIDC);
  if (coop){
    const ushort* xbc = xb; const ushort* wtc = wt;
    const int2* mgc = meta_g; const int* kpc = kptr_g;
    void* params[7] = {(void*)&x,(void*)&xbc,(void*)&mgc,(void*)&kpc,(void*)&wtc,(void*)&bias,(void*)&outp};
    hipError_t e = hipLaunchCooperativeKernel(reinterpret_cast<const void*>(fsync),
                                              dim3(GRIDC), dim3(256), params, 0, stream);
    if (e != hipSuccess){ (void)hipGetLastError(); coop=false; }
  }
  if (!coop){
    if (use_xb) k_coop<1,0><<<dim3(GRIDC), dim3(256), 0, stream>>>(x,xb,meta_g,kptr_g,wt,bias,outp);
    else        k_coop<0,0><<<dim3(GRIDC), dim3(256), 0, stream>>>(x,xb,meta_g,kptr_g,wt,bias,outp);
  }
}

// Round 9
// 2063.033 us; speedup vs baseline: 1.0955x; 1.0955x over previous
//
#include <hip/hip_runtime.h>
#include <hip/hip_cooperative_groups.h>

typedef unsigned int uint;
typedef unsigned short ushort;
typedef unsigned char uchar;

#define NLAT 361
#define NLON 720
#define NNZT 65536
#define CIN 64
#define COUT 64
#define NK 9
#define PADL 784     // 720 + 64 wrap pad
#define ROWCAP 384   // max row population ~230 (15 sigma margin)
#define CKTOT 576    // CIN*NK
#define YPS 168      // Yp row stride in ushorts (336B)
#define WTS 640      // Wt row stride in ushorts (4 chunks x 160)
#define XROWB (16*PADL*8)   // 100352 bytes per (b,lat) row of xb
#define GRIDC 722    // blocks = (lo, b); 3 pq-items each

typedef __attribute__((ext_vector_type(8))) short short8v;   // 8 bf16
typedef __attribute__((ext_vector_type(4))) float f32x4;     // MFMA C/D

__device__ __forceinline__ float bfu(uint u){ return __uint_as_float(u<<16); }
__device__ __forceinline__ float bfh(uint u){ return __uint_as_float(u & 0xffff0000u); }
__device__ __forceinline__ ushort f2bf(float f){
  uint b = __float_as_uint(f);
  return (ushort)((b + 0x7fffu + ((b>>16)&1u)) >> 16);
}
__device__ __forceinline__ uint packbf2(float f0, float f1){
  uint b0 = __float_as_uint(f0), b1 = __float_as_uint(f1);
  uint r0 = (b0 + 0x7fffu + ((b0>>16)&1u)) >> 16;
  uint r1 = ((b1 + 0x7fffu + ((b1>>16)&1u)) >> 16) << 16;
  return r0 | r1;
}

// ---- CSR build: per-row, K-MAJOR / LAT-MINOR sorted, deterministic ----------
// meta.x = lat*XROWB + lon*8 ; meta.y = (val & ~0x3ff) | lon
// kptr_g[lo*10+k] = segment start (cumulative); [9] = n
__global__ __launch_bounds__(256) void k_csr(const int* __restrict__ ker, const int* __restrict__ row,
                                             const int* __restrict__ col, const float* __restrict__ vals,
                                             int2* __restrict__ meta_g, int* __restrict__ kptr_g){
  const int lo = blockIdx.x, tid = threadIdx.x;
  __shared__ int cnt[256];
  __shared__ int2 list[ROWCAP];
  __shared__ uchar kl[ROWCAP];
  __shared__ int kc[NK];
  __shared__ int ntot;
  int c=0;
  for (int i=tid;i<NNZT;i+=256) if (row[i]==lo) c++;
  cnt[tid]=c;
  if (tid<NK) kc[tid]=0;
  __syncthreads();
  if (tid==0){ int run=0; for (int t=0;t<256;t++){ int tmp=cnt[t]; cnt[t]=run; run+=tmp; } ntot=run; }
  __syncthreads();
  int off=cnt[tid];
  for (int i=tid;i<NNZT;i+=256) if (row[i]==lo){
    if (off<ROWCAP){
      int cc=col[i]; int lat=cc/NLON, lon=cc-lat*NLON;
      uint vb=__float_as_uint(vals[i])&0xfffffc00u;
      list[off]=make_int2(lat*XROWB+lon*8, (int)(vb|(uint)lon));
      kl[off]=(uchar)ker[i];
      atomicAdd(&kc[ker[i]],1);
    }
    off++;
  }
  __syncthreads();
  int n = ntot; if (n>ROWCAP) n=ROWCAP;
  // rank sort by (k, x, insertion idx): key = (k<<23) | (x>>3)  (x<2^26, mult of 8)
  for (int i=tid;i<n;i+=256){
    uint ki = ((uint)kl[i]<<23) | ((uint)list[i].x>>3);
    int r=0;
    for (int j=0;j<n;j++){
      uint kj = ((uint)kl[j]<<23) | ((uint)list[j].x>>3);
      r += (kj<ki) || (kj==ki && j<i);
    }
    meta_g[lo*ROWCAP+r]=list[i];
  }
  if (tid==0){
    int run=0;
    for (int k=0;k<NK;k++){ kptr_g[lo*10+k]=run; run+=kc[k]; }
    kptr_g[lo*10+9]=n;
  }
}

// -- x -> bf16, layout [b][lat][cquad(16)][784 pos][4 ch], wrap-padded --------
__global__ __launch_bounds__(256) void k_xb(const float* __restrict__ x, ushort* __restrict__ xb){
  const int bid=blockIdx.x, tid=threadIdx.x;
  const int b=bid/NLAT, lat=bid-b*NLAT;
  const float* xs = x + (size_t)b*CIN*NLAT*NLON + (size_t)lat*NLON;
  ushort* xd = xb + (size_t)(b*NLAT+lat)*16*PADL*4;
  const size_t S=(size_t)NLAT*NLON;
  for (int idx=tid; idx<16*PADL; idx+=256){
    int cq=idx/PADL, j=idx-cq*PADL;
    int jj = (j<NLON)? j : j-NLON;
    const float* xc = xs + (size_t)(cq*4)*S + jj;
    uint lo32 = packbf2(xc[0], xc[S]);
    uint hi32 = packbf2(xc[2*S], xc[3*S]);
    *(uint2*)(xd + (size_t)(cq*PADL + j)*4) = make_uint2(lo32, hi32);
  }
}

// -- W -> bf16, kk-major ck order: wt[oc][chunk*160 + q*36 + kk*4 + j] --------
// source: w[oc][(chunk*16 + q*4 + j)*9 + kk]; slots 144..159 zero
__global__ __launch_bounds__(256) void k_wt(const float* __restrict__ w, ushort* __restrict__ wt){
  int idx = blockIdx.x*256 + threadIdx.x;
  if (idx >= COUT*WTS) return;
  int oc = idx/WTS, ckl = idx-oc*WTS;
  int chunk = ckl/160, q = ckl-chunk*160;
  ushort v = 0;
  if (q < 144){
    int wvq=q/36, r=q-wvq*36;
    int kk=r>>2, j=r&3;
    v = f2bf(w[oc*CKTOT + (chunk*16 + wvq*4 + j)*NK + kk]);
  }
  wt[oc*WTS + ckl] = v;
}

// ------------- phase-aligned gather + MFMA main kernel -----------------------
// block = (lo, b); 3 pq-items serial; R6-style full-n per-wave gather (wave=cquad,
// static-k segments, 8-deep unroll); SYNC=1: grid.sync per (pt,chunk) cell.
template<int USE_XB, int SYNC>
__global__ __launch_bounds__(256,4) void k_coop(const float* __restrict__ x, const ushort* __restrict__ xb,
    const int2* __restrict__ meta_g, const int* __restrict__ kptr_g,
    const ushort* __restrict__ wt, const float* __restrict__ bias, float* __restrict__ out){
  const int wid=blockIdx.x, tid=threadIdx.x;
  const int lane=tid&63, wv=tid>>6, l15=lane&15, kg=lane>>4;
  const int lo=wid>>1, b=wid&1;

  __shared__ int2 meta[ROWCAP];                    // 3072 B
  __shared__ __align__(16) ushort Yp[64*YPS];      // 21504 B -> total 24576 B

  int kp[10];
  #pragma unroll
  for (int kk=0;kk<10;kk++){ int v=kptr_g[lo*10+kk]; kp[kk]=v<ROWCAP?v:ROWCAP; }
  for (int i=tid;i<kp[9];i+=256) meta[i]=meta_g[lo*ROWCAP+i];
  // zero Yp pad rows ck 144..159 (never rewritten: writes touch ck<144)
  for (int idx=tid; idx<64*8; idx+=256){
    int p=idx>>3, j=idx&7;
    *(uint*)((char*)Yp + p*(YPS*2) + 288 + j*4)=0;
  }
  __syncthreads();

  const int wvu = __builtin_amdgcn_readfirstlane(wv);
  const char* xb8 = (const char*)xb + (size_t)b*NLAT*(size_t)XROWB;
  const char* wtb = (const char*)wt + ((wv*16+l15)*WTS + kg*8)*2;
  const char* ypb = (const char*)Yp + l15*(YPS*2) + kg*16;
  char* ydst = (char*)Yp + lane*(YPS*2) + wv*72;

#define GADDR(M) ((uint)(M).x + lanep8 + (((((uint)(M).y)&0x3ffu) >= thr) ? (uint)-5760 : 0u))
#define GVAL(M)  __uint_as_float(((uint)(M).y) & 0xfffffc00u)
#define GCONS(U,V,ACC,AI) { ACC[0][AI]+=(V)*bfu((U).x); ACC[1][AI]+=(V)*bfh((U).x); \
                            ACC[2][AI]+=(V)*bfu((U).y); ACC[3][AI]+=(V)*bfh((U).y); }
#define GB1F(M,ACC,AI) { \
      uint lon=((uint)(M).y)&0x3ffu; float v=GVAL(M); \
      int lat=(int)(((uint)(M).x)/(uint)XROWB); \
      int s=(int)lon+p0; s=(s>=NLON)?s-NLON:s; \
      int widx=s+lane; widx=(widx>=NLON)?widx-NLON:widx; \
      int fb=((b*CIN + chunk*16 + wv*4)*NLAT + lat)*NLON + widx; \
      ACC[0][AI]+=v*x[fb]; ACC[1][AI]+=v*x[fb+NLAT*NLON]; \
      ACC[2][AI]+=v*x[fb+2*NLAT*NLON]; ACC[3][AI]+=v*x[fb+3*NLAT*NLON]; }

#define GSEG(ACC,KI,AI) { \
      int i=kp[KI]; const int e=kp[(KI)+1]; \
      if (USE_XB){ \
        for (; i+7<e; i+=8){ \
          int2 m0=meta[i],m1=meta[i+1],m2=meta[i+2],m3=meta[i+3]; \
          int2 m4=meta[i+4],m5=meta[i+5],m6=meta[i+6],m7=meta[i+7]; \
          uint2 u0=*(const uint2*)(xbase+GADDR(m0)); uint2 u1=*(const uint2*)(xbase+GADDR(m1)); \
          uint2 u2=*(const uint2*)(xbase+GADDR(m2)); uint2 u3=*(const uint2*)(xbase+GADDR(m3)); \
          uint2 u4=*(const uint2*)(xbase+GADDR(m4)); uint2 u5=*(const uint2*)(xbase+GADDR(m5)); \
          uint2 u6=*(const uint2*)(xbase+GADDR(m6)); uint2 u7=*(const uint2*)(xbase+GADDR(m7)); \
          GCONS(u0,GVAL(m0),ACC,AI); GCONS(u1,GVAL(m1),ACC,AI); \
          GCONS(u2,GVAL(m2),ACC,AI); GCONS(u3,GVAL(m3),ACC,AI); \
          GCONS(u4,GVAL(m4),ACC,AI); GCONS(u5,GVAL(m5),ACC,AI); \
          GCONS(u6,GVAL(m6),ACC,AI); GCONS(u7,GVAL(m7),ACC,AI); \
        } \
        for (; i+3<e; i+=4){ \
          int2 m0=meta[i],m1=meta[i+1],m2=meta[i+2],m3=meta[i+3]; \
          uint2 u0=*(const uint2*)(xbase+GADDR(m0)); uint2 u1=*(const uint2*)(xbase+GADDR(m1)); \
          uint2 u2=*(const uint2*)(xbase+GADDR(m2)); uint2 u3=*(const uint2*)(xbase+GADDR(m3)); \
          GCONS(u0,GVAL(m0),ACC,AI); GCONS(u1,GVAL(m1),ACC,AI); \
          GCONS(u2,GVAL(m2),ACC,AI); GCONS(u3,GVAL(m3),ACC,AI); \
        } \
        for (; i<e; i++){ int2 m0=meta[i]; \
          uint2 u0=*(const uint2*)(xbase+GADDR(m0)); GCONS(u0,GVAL(m0),ACC,AI); } \
      } else { \
        for (; i<e; i++){ int2 m0=meta[i]; GB1F(m0,ACC,AI); } \
      } }

  f32x4 outacc[3][4];
  #pragma unroll
  for (int a=0;a<3;a++)
    #pragma unroll
    for (int c2=0;c2<4;c2++) outacc[a][c2]=(f32x4)0.f;

  for (int pt=0;pt<4;pt++){
    for (int chunk=0;chunk<4;chunk++){
      if constexpr (SYNC) cooperative_groups::this_grid().sync();  // phase alignment
      const char* xbase = xb8 + (size_t)(chunk*4+wvu)*(PADL*8);
      for (int it=0;it<3;it++){
        const int p0 = it*240 + pt*64;
        const uint thr = (uint)(NLON-p0);
        const uint lanep8 = (uint)(lane+p0)*8u;
        const bool act = (pt<3) || (lane<48);  // pt=3: lanes>=48 feed only discarded ptile3

        // ---- half A: kk 0..4 ----
        {
          float acc1[4][5];
          #pragma unroll
          for (int j=0;j<4;j++)
            #pragma unroll
            for (int kk=0;kk<5;kk++) acc1[j][kk]=0.f;
          if (act){ GSEG(acc1,0,0) GSEG(acc1,1,1) GSEG(acc1,2,2) GSEG(acc1,3,3) GSEG(acc1,4,4) }
          __syncthreads();   // prev item's MFMA done reading Yp
          if (act){
            #pragma unroll
            for (int kk=0;kk<5;kk++){
              *(uint*)(ydst + (kk*4+0)*2) = packbf2(acc1[0][kk], acc1[1][kk]);
              *(uint*)(ydst + (kk*4+2)*2) = packbf2(acc1[2][kk], acc1[3][kk]);
            }
          }
        }
        // ---- half B: kk 5..8 ----
        {
          float acc2[4][4];
          #pragma unroll
          for (int j=0;j<4;j++)
            #pragma unroll
            for (int kk=0;kk<4;kk++) acc2[j][kk]=0.f;
          if (act){
            GSEG(acc2,5,0) GSEG(acc2,6,1) GSEG(acc2,7,2) GSEG(acc2,8,3)
            #pragma unroll
            for (int kk=0;kk<4;kk++){
              *(uint*)(ydst + ((kk+5)*4+0)*2) = packbf2(acc2[0][kk], acc2[1][kk]);
              *(uint*)(ydst + ((kk+5)*4+2)*2) = packbf2(acc2[2][kk], acc2[3][kk]);
            }
          }
        }
        __syncthreads();   // Yp complete
        // ---- stage 2 via MFMA ----
        #pragma unroll
        for (int ptile=0;ptile<4;ptile++){
          #pragma unroll
          for (int ks=0;ks<5;ks++){
            short8v bf = *(const short8v*)(ypb + ptile*(16*YPS*2) + ks*64);
            short8v afk = *(const short8v*)(wtb + (chunk*160 + ks*32)*2);
            outacc[it][ptile]=__builtin_amdgcn_mfma_f32_16x16x32_bf16(afk,bf,outacc[it][ptile],0,0,0);
          }
        }
      }
    }
    // epilogue for this pt; D: col=l15 (p), row=kg*4+r (oc); guard pidx<240
    #pragma unroll
    for (int it=0;it<3;it++){
      #pragma unroll
      for (int ptile=0;ptile<4;ptile++){
        const int pidx = pt*64 + ptile*16;
        if (pidx < 240){
          #pragma unroll
          for (int r=0;r<4;r++){
            int oc = wv*16 + kg*4 + r;
            out[((size_t)(b*COUT+oc)*NLAT + lo)*NLON + it*240 + pidx + l15]
              = outacc[it][ptile][r] + bias[oc];
          }
        }
        outacc[it][ptile]=(f32x4)0.f;
      }
    }
  }
#undef GSEG
#undef GB1F
#undef GCONS
#undef GVAL
#undef GADDR
}

extern "C" void kernel_launch(void* const* d_in, const int* in_sizes, int n_in,
                              void* d_out, int out_size, void* d_ws, size_t ws_size,
                              hipStream_t stream){
  const float* x   =(const float*)d_in[0];
  const float* vals=(const float*)d_in[1];
  const float* w   =(const float*)d_in[2];
  const float* bias=(const float*)d_in[3];
  const int* ker=(const int*)d_in[4];
  const int* row=(const int*)d_in[5];
  const int* col=(const int*)d_in[6];
  float* outp=(float*)d_out;

  const size_t META_B=(size_t)NLAT*ROWCAP*sizeof(int2);
  const size_t KPTR_B=((size_t)NLAT*10*sizeof(int)+15)&~(size_t)15;
  const size_t WT_B=((size_t)COUT*WTS*sizeof(ushort)+15)&~(size_t)15;
  const size_t XB_B=(size_t)2*NLAT*16*PADL*4*sizeof(ushort);
  int2* meta_g=(int2*)d_ws;
  int*  kptr_g=(int*)((char*)d_ws+META_B);
  ushort* wt=(ushort*)((char*)d_ws+META_B+KPTR_B);
  ushort* xb=(ushort*)((char*)d_ws+META_B+KPTR_B+WT_B);
  const bool use_xb = ws_size >= META_B+KPTR_B+WT_B+XB_B;

  k_csr<<<dim3(NLAT), dim3(256), 0, stream>>>(ker,row,col,vals,meta_g,kptr_g);
  k_wt <<<dim3((COUT*WTS+255)/256), dim3(256), 0, stream>>>(w, wt);
  if (use_xb)
    k_xb<<<dim3(2*NLAT), dim3(256), 0, stream>>>(x, xb);

  // host-side capability + co-residency checks (capture-safe pure queries)
  int dev=0; (void)hipGetDevice(&dev);
  int coopAttr=0; (void)hipDeviceGetAttribute(&coopAttr, hipDeviceAttributeCooperativeLaunch, dev);
  int ncu=0; (void)hipDeviceGetAttribute(&ncu, hipDeviceAttributeMultiprocessorCount, dev);

  typedef void (*KFn)(const float*, const ushort*, const int2*, const int*,
                      const ushort*, const float*, float*);
  KFn fsync = use_xb ? (KFn)&k_coop<1,1> : (KFn)&k_coop<0,1>;
  int nb=0;
  (void)hipOccupancyMaxActiveBlocksPerMultiprocessor(&nb, fsync, 256, 0);

  bool coop = (coopAttr!=0) && ((long)nb*(long)ncu >= (long)GRIDC);
  if (coop){
    const ushort* xbc = xb; const ushort* wtc = wt;
    const int2* mgc = meta_g; const int* kpc = kptr_g;
    void* params[7] = {(void*)&x,(void*)&xbc,(void*)&mgc,(void*)&kpc,(void*)&wtc,(void*)&bias,(void*)&outp};
    hipError_t e = hipLaunchCooperativeKernel(reinterpret_cast<const void*>(fsync),
                                              dim3(GRIDC), dim3(256), params, 0, stream);
    if (e != hipSuccess){ (void)hipGetLastError(); coop=false; }
  }
  if (!coop){
    if (use_xb) k_coop<1,0><<<dim3(GRIDC), dim3(256), 0, stream>>>(x,xb,meta_g,kptr_g,wt,bias,outp);
    else        k_coop<0,0><<<dim3(GRIDC), dim3(256), 0, stream>>>(x,xb,meta_g,kptr_g,wt,bias,outp);
  }
}